// Round 12
// baseline (315.399 us; speedup 1.0000x reference)
//
#include <hip/hip_runtime.h>
#include <hip/hip_cooperative_groups.h>
#include <math.h>

namespace cg = cooperative_groups;

// N=100000, E=500000, D=256.
// Factored: concat(h[s],h[d])@W1 == h[s]@W1[0:256] + h[d]@W1[256:512]
//
// R20: ONE cooperative kernel (build_wt -> grid.sync -> gemm -> grid.sync
// -> edge), grid 256x512 = 1 block/CU (co-resident). Phase bodies are the
// PROVEN R19 bodies re-indexed. Rationale: gemm frozen at 78us (6 failed
// restructures; per-phase models under-predict 3x — stop), edge is
// BW-bound at its ~60us fabric floor (R6->R7: 2x in-flight ~ null), so
// the remaining controllable cost is the ~87us opaque inter-dispatch
// region. Fusion removes 2 launch gaps + build_wt dispatch. Edge at 8
// waves/CU is safe: BW-bound, 64KB/CU in flight >> ~12KB latency-BW
// product. Runtime FALLBACK: if hipLaunchCooperativeKernel errors (e.g.
// graph-capture unsupported), the R19 3-dispatch path runs.
// fp8 error budget unchanged: absmax 0.0078 << 0.0156 threshold.

typedef __attribute__((ext_vector_type(8))) short short8;
typedef __attribute__((ext_vector_type(2))) float floatx2;
typedef __attribute__((ext_vector_type(4))) float floatx4;
typedef __attribute__((ext_vector_type(16))) float floatx16;

#define D_FEAT 256
#define EPW 16

__device__ __forceinline__ float bf2f(unsigned short u) {
    union { unsigned u32; float f; } v; v.u32 = ((unsigned)u) << 16; return v.f;
}
__device__ __forceinline__ float lo16(unsigned u) {
    union { unsigned u32; float f; } v; v.u32 = u << 16; return v.f;
}
__device__ __forceinline__ float hi16(unsigned u) {
    union { unsigned u32; float f; } v; v.u32 = u & 0xffff0000u; return v.f;
}
__device__ __forceinline__ unsigned short f2bf(float f) {
    union { float f; unsigned u32; } v; v.f = f;
    unsigned x = v.u32;
    return (unsigned short)((x + 0x7fffu + ((x >> 16) & 1u)) >> 16);
}
__device__ __forceinline__ float sigmoid_safe(float r) {
    r = fminf(fmaxf(r, -30.f), 30.f);
    return 1.f / (1.f + expf(-r));
}
// 4 floats -> 4 fp8 e4m3 bytes (HW cvt, RNE)
__device__ __forceinline__ unsigned pack4_fp8(float a, float b, float c, float d) {
    int w = __builtin_amdgcn_cvt_pk_fp8_f32(a, b, 0, false);
    w = __builtin_amdgcn_cvt_pk_fp8_f32(c, d, w, true);
    return (unsigned)w;
}

// ---- dtype probe core: bf16 N(0,1) shorts have exp field in [100,140]
// ~100% of the time; fp32 reinterpreted as shorts only ~58%. Threshold
// 1843/2048 (90%). 256-thread variant (fallback kernels).
__device__ __forceinline__ int probe_block(const unsigned short* __restrict__ h,
                                           int tid) {
    __shared__ int cnt_s[4];
    int c = 0;
    #pragma unroll
    for (int i = 0; i < 8; ++i) {
        unsigned e = (h[tid * 8 + i] >> 7) & 0xFF;
        c += (e >= 100 && e <= 140) ? 1 : 0;
    }
    #pragma unroll
    for (int off = 32; off > 0; off >>= 1)
        c += __shfl_xor(c, off);
    if ((tid & 63) == 0) cnt_s[tid >> 6] = c;
    __syncthreads();
    int s = cnt_s[0] + cnt_s[1] + cnt_s[2] + cnt_s[3];
    return (s >= 1843) ? 1 : 0;
}

// Standalone probe (fallback path only).
__global__ __launch_bounds__(256) void probe_dtype(const unsigned short* __restrict__ h,
                                                   int* __restrict__ flag) {
    int isbf16 = probe_block(h, threadIdx.x);
    if (threadIdx.x == 0) flag[0] = isbf16;
}

// Wt[j][k] bf16 [512,256]: j<256 -> W1[k][j]; j>=256 -> W1[256+k][j-256]
__global__ __launch_bounds__(256) void build_wt(const unsigned short* __restrict__ h,
                                                const void* __restrict__ W1v,
                                                unsigned short* __restrict__ Wt,
                                                int* __restrict__ flag) {
    const int isbf16 = probe_block(h, threadIdx.x);
    if (blockIdx.x == 0 && threadIdx.x == 0) flag[0] = isbf16;
    int j = blockIdx.x, k = threadIdx.x;
    size_t idx = (j < 256) ? ((size_t)k * 256 + j) : ((size_t)(k + 256) * 256 + (j - 256));
    unsigned short v;
    if (isbf16) v = ((const unsigned short*)W1v)[idx];
    else        v = f2bf(((const float*)W1v)[idx]);
    Wt[(size_t)j * 256 + k] = v;
}

// ======================= R20 fused cooperative kernel =======================
// Phase 0: build Wt (2 j's per block). Phase 1: R19 gemm body. Phase 2:
// R15 edge body, grid-stride over 16-edge wave-groups.
__global__ __launch_bounds__(512, 2) void fused_all(const unsigned short* __restrict__ hu,
                                                    const void* __restrict__ W1v,
                                                    const int* __restrict__ src,
                                                    const int* __restrict__ dst,
                                                    const void* __restrict__ b1v,
                                                    const void* __restrict__ W2v,
                                                    const void* __restrict__ b2v,
                                                    unsigned short* __restrict__ Wt,
                                                    unsigned char* __restrict__ PQ8,
                                                    void* __restrict__ outv,
                                                    int N, int E) {
    __shared__ unsigned short Bs[256][256];   // 128 KB (gemm); probe scratch
    __shared__ unsigned short As[64][256];    // 32 KB (gemm A tile / fp8 scratch)
    cg::grid_group grid = cg::this_grid();

    const int tid  = threadIdx.x;
    const int lane = tid & 63;
    const int wid  = tid >> 6;       // 0..7
    const int l32  = lane & 31;
    const int q2   = lane >> 5;

    // ---- probe (512-thread variant: 4 shorts each over the same first
    // 2048 shorts, same threshold — semantics identical to probe_block).
    int isbf16;
    {
        int* cnt_s = (int*)&Bs[0][0];   // reuse LDS (Bs staged later)
        int c = 0;
        #pragma unroll
        for (int i = 0; i < 4; ++i) {
            unsigned e = (hu[tid * 4 + i] >> 7) & 0xFF;
            c += (e >= 100 && e <= 140) ? 1 : 0;
        }
        #pragma unroll
        for (int off = 32; off > 0; off >>= 1)
            c += __shfl_xor(c, off);
        if ((tid & 63) == 0) cnt_s[tid >> 6] = c;
        __syncthreads();
        int s = 0;
        #pragma unroll
        for (int i = 0; i < 8; ++i) s += cnt_s[i];
        isbf16 = (s >= 1843) ? 1 : 0;
        __syncthreads();   // cnt_s reads done before Bs is staged
    }

    // ---- Phase 0: build Wt. 256 blocks x 512 thr = 512 j x 256 k.
    {
        const int j = blockIdx.x * 2 + (tid >> 8);
        const int k = tid & 255;
        size_t idx = (j < 256) ? ((size_t)k * 256 + j)
                               : ((size_t)(k + 256) * 256 + (j - 256));
        unsigned short v;
        if (isbf16) v = ((const unsigned short*)W1v)[idx];
        else        v = f2bf(((const float*)W1v)[idx]);
        Wt[(size_t)j * 256 + k] = v;
    }
    grid.sync();

    // ---- Phase 1: gemm (R19 proven body, verbatim).
    {
        const void* hv = (const void*)hu;
        // Stage Bs once (Wt rows 0..255), swizzled write: conflict-free.
        {
            const int r = tid >> 1;
            const unsigned cbase = (tid & 1) * 256;
            const char* srcp = (const char*)Wt + (size_t)r * 512 + cbase;
            char* dstb = (char*)&Bs[0][0] + (unsigned)r * 512;
            const unsigned sw = ((unsigned)r & 31) << 4;
            #pragma unroll
            for (int i = 0; i < 16; ++i) {
                short8 v = *(const short8*)(srcp + i * 16);
                *(short8*)(dstb + ((cbase + i * 16) ^ sw)) = v;
            }
        }

        // Reg-B: Wt row (256 + wid*32 + l32), k-slot = ks*32 + q2*16 bytes.
        short8 breg[16];
        {
            const char* bp = (const char*)Wt + (size_t)(256 + wid * 32 + l32) * 512 + q2 * 16;
            #pragma unroll
            for (int ks = 0; ks < 16; ++ks)
                breg[ks] = *(const short8*)(bp + ks * 32);
        }

        // A staging map: thread t -> row ar (0..63), 4 x 16 B at col ac.
        const int ar = tid >> 3;
        const unsigned ac = (unsigned)(tid & 7) * 64;
        const unsigned aswz = ((unsigned)ar & 31) << 4;

        short8 pref[4];
        auto load_a = [&](int ms) {
            const int gm = ms * 64 + ar;
            if (isbf16) {
                #pragma unroll
                for (int j = 0; j < 4; ++j) {
                    short8 v = {};
                    if (gm < N)
                        v = *(const short8*)((const char*)hv + (size_t)gm * 512 + ac + j * 16);
                    pref[j] = v;
                }
            } else {
                #pragma unroll
                for (int j = 0; j < 4; ++j) {
                    short8 v = {};
                    if (gm < N) {
                        const float* p = (const float*)hv + (size_t)gm * 256 + (ac + j * 16) / 2;
                        floatx4 f0 = *(const floatx4*)p;
                        floatx4 f1 = *(const floatx4*)(p + 4);
                        v[0] = (short)f2bf(f0.x); v[1] = (short)f2bf(f0.y);
                        v[2] = (short)f2bf(f0.z); v[3] = (short)f2bf(f0.w);
                        v[4] = (short)f2bf(f1.x); v[5] = (short)f2bf(f1.y);
                        v[6] = (short)f2bf(f1.z); v[7] = (short)f2bf(f1.w);
                    }
                    pref[j] = v;
                }
            }
        };

        const int NT = (N + 63) >> 6;
        const int GM = gridDim.x;
        if ((int)blockIdx.x < NT) load_a(blockIdx.x);

        for (int ms = blockIdx.x; ms < NT; ms += GM) {
            __syncthreads();   // bar1: prev scratch readout done -> As writable
            {
                char* adst = (char*)&As[0][0] + (unsigned)ar * 512;
                #pragma unroll
                for (int j = 0; j < 4; ++j)
                    *(short8*)(adst + ((ac + j * 16) ^ aswz)) = pref[j];
            }
            __syncthreads();   // bar2: As visible

            const int msn = ms + GM;
            if (msn < NT) load_a(msn);   // covered by K-loop

            floatx16 acc[2][2] = {};
            #pragma unroll
            for (int ks = 0; ks < 16; ++ks) {
                const unsigned cb = ((unsigned)(ks * 32 + q2 * 16)) ^ ((unsigned)l32 << 4);
                short8 a0 = *(const short8*)((const char*)&As[0][0] + (unsigned)l32 * 512 + cb);
                short8 a1 = *(const short8*)((const char*)&As[0][0] + (unsigned)(32 + l32) * 512 + cb);
                short8 bl = *(const short8*)((const char*)&Bs[0][0] + (unsigned)(wid * 32 + l32) * 512 + cb);
                acc[0][0] = __builtin_amdgcn_mfma_f32_32x32x16_bf16(bl,       a0, acc[0][0], 0, 0, 0);
                acc[1][0] = __builtin_amdgcn_mfma_f32_32x32x16_bf16(bl,       a1, acc[1][0], 0, 0, 0);
                acc[0][1] = __builtin_amdgcn_mfma_f32_32x32x16_bf16(breg[ks], a0, acc[0][1], 0, 0, 0);
                acc[1][1] = __builtin_amdgcn_mfma_f32_32x32x16_bf16(breg[ks], a1, acc[1][1], 0, 0, 0);
            }

            __syncthreads();   // bar3: As reads done -> reuse as fp8 scratch
            {
                unsigned char* scr = (unsigned char*)&As[0][0];
                #pragma unroll
                for (int mi = 0; mi < 2; ++mi) {
                    const unsigned row = (unsigned)(mi * 32 + l32);
                    const unsigned rs = (row & 31) << 4;
                    #pragma unroll
                    for (int nb = 0; nb < 2; ++nb) {
                        const unsigned nbase = (unsigned)(nb * 256 + wid * 32 + 4 * q2);
                        #pragma unroll
                        for (int g = 0; g < 4; ++g) {
                            unsigned w = pack4_fp8(acc[mi][nb][4 * g + 0], acc[mi][nb][4 * g + 1],
                                                   acc[mi][nb][4 * g + 2], acc[mi][nb][4 * g + 3]);
                            const unsigned col = nbase + 8 * g;
                            *(unsigned*)(scr + ((row * 512 + col) ^ rs)) = w;
                        }
                    }
                }
            }
            __syncthreads();   // bar4: scratch complete -> coalesced readout
            {
                const unsigned char* scr = (const unsigned char*)&As[0][0];
                const int gm = ms * 64 + ar;
                if (gm < N) {
                    #pragma unroll
                    for (int j = 0; j < 4; ++j) {
                        const unsigned col = ac + j * 16;
                        uint4 v = *(const uint4*)(scr + (((unsigned)ar * 512 + col) ^ aswz));
                        *(uint4*)(PQ8 + (size_t)gm * 512 + col) = v;
                    }
                }
            }
        }
    }
    grid.sync();

    // ---- Phase 2: edge (R15 proven body, grid-stride over wave-groups).
    {
        const int par = lane >> 5;
        float bf[8], wf[8];
        if (isbf16) {
            const uint4 bvr = *(const uint4*)((const unsigned short*)b1v + l32 * 8);
            const uint4 wvr = *(const uint4*)((const unsigned short*)W2v + l32 * 8);
            bf[0] = lo16(bvr.x); bf[1] = hi16(bvr.x); bf[2] = lo16(bvr.y); bf[3] = hi16(bvr.y);
            bf[4] = lo16(bvr.z); bf[5] = hi16(bvr.z); bf[6] = lo16(bvr.w); bf[7] = hi16(bvr.w);
            wf[0] = lo16(wvr.x); wf[1] = hi16(wvr.x); wf[2] = lo16(wvr.y); wf[3] = hi16(wvr.y);
            wf[4] = lo16(wvr.z); wf[5] = hi16(wvr.z); wf[6] = lo16(wvr.w); wf[7] = hi16(wvr.w);
        } else {
            const float* bp = (const float*)b1v + l32 * 8;
            const float* wp = (const float*)W2v + l32 * 8;
            #pragma unroll
            for (int t = 0; t < 8; ++t) { bf[t] = bp[t]; wf[t] = wp[t]; }
        }
        float bias2;
        if (isbf16) bias2 = bf2f(((const unsigned short*)b2v)[0]);
        else        bias2 = ((const float*)b2v)[0];

        const int gstep = gridDim.x * 8;            // wave-groups per sweep
        for (int g = blockIdx.x * 8 + wid; (long)g * EPW < E; g += gstep) {
            const int e0 = g * EPW;

            int nsrc[8], ndst[8];
            #pragma unroll
            for (int p = 0; p < 8; ++p) {
                int e = e0 + 2 * p + par; if (e >= E) e = E - 1;
                nsrc[p] = src[e];
                ndst[p] = dst[e];
            }
            uint2 rp[8], rq[8];
            #pragma unroll
            for (int p = 0; p < 8; ++p) {
                rp[p] = *(const uint2*)(PQ8 + (size_t)nsrc[p] * 512 + l32 * 8);
                rq[p] = *(const uint2*)(PQ8 + (size_t)ndst[p] * 512 + 256 + l32 * 8);
            }

            float res[8];
            #pragma unroll
            for (int p = 0; p < 8; ++p) {
                floatx2 p01 = __builtin_amdgcn_cvt_pk_f32_fp8((int)rp[p].x, false);
                floatx2 p23 = __builtin_amdgcn_cvt_pk_f32_fp8((int)rp[p].x, true);
                floatx2 p45 = __builtin_amdgcn_cvt_pk_f32_fp8((int)rp[p].y, false);
                floatx2 p67 = __builtin_amdgcn_cvt_pk_f32_fp8((int)rp[p].y, true);
                floatx2 q01 = __builtin_amdgcn_cvt_pk_f32_fp8((int)rq[p].x, false);
                floatx2 q23 = __builtin_amdgcn_cvt_pk_f32_fp8((int)rq[p].x, true);
                floatx2 q45 = __builtin_amdgcn_cvt_pk_f32_fp8((int)rq[p].y, false);
                floatx2 q67 = __builtin_amdgcn_cvt_pk_f32_fp8((int)rq[p].y, true);
                float v0 = fmaxf(p01.x + q01.x + bf[0], 0.f);
                float v1 = fmaxf(p01.y + q01.y + bf[1], 0.f);
                float v2 = fmaxf(p23.x + q23.x + bf[2], 0.f);
                float v3 = fmaxf(p23.y + q23.y + bf[3], 0.f);
                float v4 = fmaxf(p45.x + q45.x + bf[4], 0.f);
                float v5 = fmaxf(p45.y + q45.y + bf[5], 0.f);
                float v6 = fmaxf(p67.x + q67.x + bf[6], 0.f);
                float v7 = fmaxf(p67.y + q67.y + bf[7], 0.f);
                res[p] = v0 * wf[0] + v1 * wf[1] + v2 * wf[2] + v3 * wf[3]
                       + v4 * wf[4] + v5 * wf[5] + v6 * wf[6] + v7 * wf[7];
            }

            float t4[4];
            #pragma unroll
            for (int k = 0; k < 4; ++k) {
                float a = res[2 * k], b = res[2 * k + 1];
                float own  = (lane & 1) ? b : a;
                float send = (lane & 1) ? a : b;
                t4[k] = own + __shfl_xor(send, 1);
            }
            float t2[2];
            #pragma unroll
            for (int k = 0; k < 2; ++k) {
                float a = t4[2 * k], b = t4[2 * k + 1];
                float own  = (lane & 2) ? b : a;
                float send = (lane & 2) ? a : b;
                t2[k] = own + __shfl_xor(send, 2);
            }
            float t1;
            {
                float a = t2[0], b = t2[1];
                float own  = (lane & 4) ? b : a;
                float send = (lane & 4) ? a : b;
                t1 = own + __shfl_xor(send, 4);
            }
            t1 += __shfl_xor(t1, 8);
            t1 += __shfl_xor(t1, 16);

            if (l32 < 8) {
                const int e = e0 + 2 * (lane & 7) + par;
                if (e < E) {
                    float r = sigmoid_safe(t1 + bias2);
                    if (isbf16) ((unsigned short*)outv)[e] = f2bf(r);
                    else        ((float*)outv)[e] = r;
                }
            }
        }
    }
}

// ====================== R19 fallback kernels (unchanged) ======================

__global__ __launch_bounds__(512, 2) void gemm_pq(const void* __restrict__ hv,
                                                  const unsigned short* __restrict__ Wt,
                                                  unsigned char* __restrict__ PQ8,
                                                  int N, const int* __restrict__ flag) {
    const int isbf16 = flag[0];
    __shared__ unsigned short Bs[256][256];
    __shared__ unsigned short As[64][256];

    const int tid  = threadIdx.x;
    const int lane = tid & 63;
    const int wid  = tid >> 6;
    const int l32  = lane & 31;
    const int q2   = lane >> 5;

    {
        const int r = tid >> 1;
        const unsigned cbase = (tid & 1) * 256;
        const char* srcp = (const char*)Wt + (size_t)r * 512 + cbase;
        char* dstb = (char*)&Bs[0][0] + (unsigned)r * 512;
        const unsigned sw = ((unsigned)r & 31) << 4;
        #pragma unroll
        for (int i = 0; i < 16; ++i) {
            short8 v = *(const short8*)(srcp + i * 16);
            *(short8*)(dstb + ((cbase + i * 16) ^ sw)) = v;
        }
    }

    short8 breg[16];
    {
        const char* bp = (const char*)Wt + (size_t)(256 + wid * 32 + l32) * 512 + q2 * 16;
        #pragma unroll
        for (int ks = 0; ks < 16; ++ks)
            breg[ks] = *(const short8*)(bp + ks * 32);
    }

    const int ar = tid >> 3;
    const unsigned ac = (unsigned)(tid & 7) * 64;
    const unsigned aswz = ((unsigned)ar & 31) << 4;

    short8 pref[4];
    auto load_a = [&](int ms) {
        const int gm = ms * 64 + ar;
        if (isbf16) {
            #pragma unroll
            for (int j = 0; j < 4; ++j) {
                short8 v = {};
                if (gm < N)
                    v = *(const short8*)((const char*)hv + (size_t)gm * 512 + ac + j * 16);
                pref[j] = v;
            }
        } else {
            #pragma unroll
            for (int j = 0; j < 4; ++j) {
                short8 v = {};
                if (gm < N) {
                    const float* p = (const float*)hv + (size_t)gm * 256 + (ac + j * 16) / 2;
                    floatx4 f0 = *(const floatx4*)p;
                    floatx4 f1 = *(const floatx4*)(p + 4);
                    v[0] = (short)f2bf(f0.x); v[1] = (short)f2bf(f0.y);
                    v[2] = (short)f2bf(f0.z); v[3] = (short)f2bf(f0.w);
                    v[4] = (short)f2bf(f1.x); v[5] = (short)f2bf(f1.y);
                    v[6] = (short)f2bf(f1.z); v[7] = (short)f2bf(f1.w);
                }
                pref[j] = v;
            }
        }
    };

    const int NT = (N + 63) >> 6;
    const int GM = gridDim.x;
    if ((int)blockIdx.x < NT) load_a(blockIdx.x);

    for (int ms = blockIdx.x; ms < NT; ms += GM) {
        __syncthreads();
        {
            char* adst = (char*)&As[0][0] + (unsigned)ar * 512;
            #pragma unroll
            for (int j = 0; j < 4; ++j)
                *(short8*)(adst + ((ac + j * 16) ^ aswz)) = pref[j];
        }
        __syncthreads();

        const int msn = ms + GM;
        if (msn < NT) load_a(msn);

        floatx16 acc[2][2] = {};
        #pragma unroll
        for (int ks = 0; ks < 16; ++ks) {
            const unsigned cb = ((unsigned)(ks * 32 + q2 * 16)) ^ ((unsigned)l32 << 4);
            short8 a0 = *(const short8*)((const char*)&As[0][0] + (unsigned)l32 * 512 + cb);
            short8 a1 = *(const short8*)((const char*)&As[0][0] + (unsigned)(32 + l32) * 512 + cb);
            short8 bl = *(const short8*)((const char*)&Bs[0][0] + (unsigned)(wid * 32 + l32) * 512 + cb);
            acc[0][0] = __builtin_amdgcn_mfma_f32_32x32x16_bf16(bl,       a0, acc[0][0], 0, 0, 0);
            acc[1][0] = __builtin_amdgcn_mfma_f32_32x32x16_bf16(bl,       a1, acc[1][0], 0, 0, 0);
            acc[0][1] = __builtin_amdgcn_mfma_f32_32x32x16_bf16(breg[ks], a0, acc[0][1], 0, 0, 0);
            acc[1][1] = __builtin_amdgcn_mfma_f32_32x32x16_bf16(breg[ks], a1, acc[1][1], 0, 0, 0);
        }

        __syncthreads();
        {
            unsigned char* scr = (unsigned char*)&As[0][0];
            #pragma unroll
            for (int mi = 0; mi < 2; ++mi) {
                const unsigned row = (unsigned)(mi * 32 + l32);
                const unsigned rs = (row & 31) << 4;
                #pragma unroll
                for (int nb = 0; nb < 2; ++nb) {
                    const unsigned nbase = (unsigned)(nb * 256 + wid * 32 + 4 * q2);
                    #pragma unroll
                    for (int g = 0; g < 4; ++g) {
                        unsigned w = pack4_fp8(acc[mi][nb][4 * g + 0], acc[mi][nb][4 * g + 1],
                                               acc[mi][nb][4 * g + 2], acc[mi][nb][4 * g + 3]);
                        const unsigned col = nbase + 8 * g;
                        *(unsigned*)(scr + ((row * 512 + col) ^ rs)) = w;
                    }
                }
            }
        }
        __syncthreads();
        {
            const unsigned char* scr = (const unsigned char*)&As[0][0];
            const int gm = ms * 64 + ar;
            if (gm < N) {
                #pragma unroll
                for (int j = 0; j < 4; ++j) {
                    const unsigned col = ac + j * 16;
                    uint4 v = *(const uint4*)(scr + (((unsigned)ar * 512 + col) ^ aswz));
                    *(uint4*)(PQ8 + (size_t)gm * 512 + col) = v;
                }
            }
        }
    }
}

__global__ __launch_bounds__(256) void edge_score(const unsigned char* __restrict__ PQ8,
                                                  const int* __restrict__ src,
                                                  const int* __restrict__ dst,
                                                  const void* __restrict__ b1v,
                                                  const void* __restrict__ W2v,
                                                  const void* __restrict__ b2v,
                                                  void* __restrict__ outv,
                                                  int E, const int* __restrict__ flag) {
    const int isbf16 = flag[0];
    const int wave = threadIdx.x >> 6;
    const int lane = threadIdx.x & 63;
    const int e0 = (blockIdx.x * 4 + wave) * EPW;
    if (e0 >= E) return;
    const int l32 = lane & 31;
    const int par = lane >> 5;

    float bf[8], wf[8];
    if (isbf16) {
        const uint4 bvr = *(const uint4*)((const unsigned short*)b1v + l32 * 8);
        const uint4 wvr = *(const uint4*)((const unsigned short*)W2v + l32 * 8);
        bf[0] = lo16(bvr.x); bf[1] = hi16(bvr.x); bf[2] = lo16(bvr.y); bf[3] = hi16(bvr.y);
        bf[4] = lo16(bvr.z); bf[5] = hi16(bvr.z); bf[6] = lo16(bvr.w); bf[7] = hi16(bvr.w);
        wf[0] = lo16(wvr.x); wf[1] = hi16(wvr.x); wf[2] = lo16(wvr.y); wf[3] = hi16(wvr.y);
        wf[4] = lo16(wvr.z); wf[5] = hi16(wvr.z); wf[6] = lo16(wvr.w); wf[7] = hi16(wvr.w);
    } else {
        const float* bp = (const float*)b1v + l32 * 8;
        const float* wp = (const float*)W2v + l32 * 8;
        #pragma unroll
        for (int t = 0; t < 8; ++t) { bf[t] = bp[t]; wf[t] = wp[t]; }
    }
    float bias2;
    if (isbf16) bias2 = bf2f(((const unsigned short*)b2v)[0]);
    else        bias2 = ((const float*)b2v)[0];

    int nsrc[8], ndst[8];
    #pragma unroll
    for (int p = 0; p < 8; ++p) {
        int e = e0 + 2 * p + par; if (e >= E) e = E - 1;
        nsrc[p] = src[e];
        ndst[p] = dst[e];
    }
    uint2 rp[8], rq[8];
    #pragma unroll
    for (int p = 0; p < 8; ++p) {
        rp[p] = *(const uint2*)(PQ8 + (size_t)nsrc[p] * 512 + l32 * 8);
        rq[p] = *(const uint2*)(PQ8 + (size_t)ndst[p] * 512 + 256 + l32 * 8);
    }

    float res[8];
    #pragma unroll
    for (int p = 0; p < 8; ++p) {
        floatx2 p01 = __builtin_amdgcn_cvt_pk_f32_fp8((int)rp[p].x, false);
        floatx2 p23 = __builtin_amdgcn_cvt_pk_f32_fp8((int)rp[p].x, true);
        floatx2 p45 = __builtin_amdgcn_cvt_pk_f32_fp8((int)rp[p].y, false);
        floatx2 p67 = __builtin_amdgcn_cvt_pk_f32_fp8((int)rp[p].y, true);
        floatx2 q01 = __builtin_amdgcn_cvt_pk_f32_fp8((int)rq[p].x, false);
        floatx2 q23 = __builtin_amdgcn_cvt_pk_f32_fp8((int)rq[p].x, true);
        floatx2 q45 = __builtin_amdgcn_cvt_pk_f32_fp8((int)rq[p].y, false);
        floatx2 q67 = __builtin_amdgcn_cvt_pk_f32_fp8((int)rq[p].y, true);
        float v0 = fmaxf(p01.x + q01.x + bf[0], 0.f);
        float v1 = fmaxf(p01.y + q01.y + bf[1], 0.f);
        float v2 = fmaxf(p23.x + q23.x + bf[2], 0.f);
        float v3 = fmaxf(p23.y + q23.y + bf[3], 0.f);
        float v4 = fmaxf(p45.x + q45.x + bf[4], 0.f);
        float v5 = fmaxf(p45.y + q45.y + bf[5], 0.f);
        float v6 = fmaxf(p67.x + q67.x + bf[6], 0.f);
        float v7 = fmaxf(p67.y + q67.y + bf[7], 0.f);
        res[p] = v0 * wf[0] + v1 * wf[1] + v2 * wf[2] + v3 * wf[3]
               + v4 * wf[4] + v5 * wf[5] + v6 * wf[6] + v7 * wf[7];
    }

    float t4[4];
    #pragma unroll
    for (int k = 0; k < 4; ++k) {
        float a = res[2 * k], b = res[2 * k + 1];
        float own  = (lane & 1) ? b : a;
        float send = (lane & 1) ? a : b;
        t4[k] = own + __shfl_xor(send, 1);
    }
    float t2[2];
    #pragma unroll
    for (int k = 0; k < 2; ++k) {
        float a = t4[2 * k], b = t4[2 * k + 1];
        float own  = (lane & 2) ? b : a;
        float send = (lane & 2) ? a : b;
        t2[k] = own + __shfl_xor(send, 2);
    }
    float t1;
    {
        float a = t2[0], b = t2[1];
        float own  = (lane & 4) ? b : a;
        float send = (lane & 4) ? a : b;
        t1 = own + __shfl_xor(send, 4);
    }
    t1 += __shfl_xor(t1, 8);
    t1 += __shfl_xor(t1, 16);

    if (l32 < 8) {
        const int e = e0 + 2 * (lane & 7) + par;
        if (e < E) {
            float r = sigmoid_safe(t1 + bias2);
            if (isbf16) ((unsigned short*)outv)[e] = f2bf(r);
            else        ((float*)outv)[e] = r;
        }
    }
}

// Zero-workspace fallback: one block per edge (full precision, no PQ).
__global__ __launch_bounds__(256) void edge_fused(const void* __restrict__ hv,
                                                  const int* __restrict__ src,
                                                  const int* __restrict__ dst,
                                                  const void* __restrict__ W1v,
                                                  const void* __restrict__ b1v,
                                                  const void* __restrict__ W2v,
                                                  const void* __restrict__ b2v,
                                                  void* __restrict__ outv,
                                                  int E, const int* __restrict__ flag) {
    const int isbf16 = flag ? flag[0] : 1;
    __shared__ float he[512];
    __shared__ float wsum[4];
    const int e = blockIdx.x;
    if (e >= E) return;
    const int t = threadIdx.x;
    const int s = src[e];
    const int d = dst[e];

    if (isbf16) {
        he[t]       = bf2f(((const unsigned short*)hv)[(size_t)s * 256 + t]);
        he[256 + t] = bf2f(((const unsigned short*)hv)[(size_t)d * 256 + t]);
    } else {
        he[t]       = ((const float*)hv)[(size_t)s * 256 + t];
        he[256 + t] = ((const float*)hv)[(size_t)d * 256 + t];
    }
    __syncthreads();

    float acc;
    if (isbf16) acc = bf2f(((const unsigned short*)b1v)[t]);
    else        acc = ((const float*)b1v)[t];

    #pragma unroll 8
    for (int k = 0; k < 512; ++k) {
        float w;
        if (isbf16) w = bf2f(((const unsigned short*)W1v)[(size_t)k * 256 + t]);
        else        w = ((const float*)W1v)[(size_t)k * 256 + t];
        acc += he[k] * w;
    }

    float w2;
    if (isbf16) w2 = bf2f(((const unsigned short*)W2v)[t]);
    else        w2 = ((const float*)W2v)[t];
    acc = fmaxf(acc, 0.f) * w2;

    #pragma unroll
    for (int off = 32; off > 0; off >>= 1)
        acc += __shfl_xor(acc, off);
    if ((t & 63) == 0) wsum[t >> 6] = acc;
    __syncthreads();

    if (t == 0) {
        float bias2;
        if (isbf16) bias2 = bf2f(((const unsigned short*)b2v)[0]);
        else        bias2 = ((const float*)b2v)[0];
        float r = sigmoid_safe(wsum[0] + wsum[1] + wsum[2] + wsum[3] + bias2);
        if (isbf16) ((unsigned short*)outv)[e] = f2bf(r);
        else        ((float*)outv)[e] = r;
    }
}

extern "C" void kernel_launch(void* const* d_in, const int* in_sizes, int n_in,
                              void* d_out, int out_size, void* d_ws, size_t ws_size,
                              hipStream_t stream) {
    const void* h  = d_in[0];
    const int* src = (const int*)d_in[1];
    const int* dst = (const int*)d_in[2];
    const void* W1 = d_in[3];
    const void* b1 = d_in[4];
    const void* W2 = d_in[5];
    const void* b2 = d_in[6];

    const int N = in_sizes[0] / D_FEAT;   // 100000
    const int E = in_sizes[1];            // 500000

    const size_t FLAG_BYTES = 256;
    const size_t wt_bytes  = (size_t)512 * D_FEAT * sizeof(unsigned short);
    const size_t pq_bytes  = (size_t)N * 512;   // fp8: 1 B/elem
    const size_t need = FLAG_BYTES + wt_bytes + pq_bytes;

    int* flag = (int*)d_ws;
    unsigned short* Wt = (unsigned short*)((char*)d_ws + FLAG_BYTES);
    unsigned char*  PQ8 = (unsigned char*)((char*)d_ws + FLAG_BYTES + wt_bytes);

    if (ws_size >= need) {
        // R20: single cooperative launch (build_wt -> gemm -> edge).
        const unsigned short* hu = (const unsigned short*)h;
        void* outv = d_out;
        int Nv = N, Ev = E;
        void* kargs[] = { (void*)&hu, (void*)&W1, (void*)&src, (void*)&dst,
                          (void*)&b1, (void*)&W2, (void*)&b2, (void*)&Wt,
                          (void*)&PQ8, (void*)&outv, (void*)&Nv, (void*)&Ev };
        hipError_t err = hipLaunchCooperativeKernel((const void*)fused_all,
                                                    dim3(256), dim3(512),
                                                    kargs, 0, stream);
        if (err != hipSuccess) {
            // R19 fallback: 3 plain dispatches.
            build_wt<<<512, 256, 0, stream>>>((const unsigned short*)h, W1, Wt, flag);
            gemm_pq<<<256, 512, 0, stream>>>(h, Wt, PQ8, N, flag);
            int egrid = (E + 4 * EPW - 1) / (4 * EPW);
            edge_score<<<egrid, 256, 0, stream>>>(PQ8, src, dst, b1, W2, b2, d_out, E, flag);
        }
    } else if (ws_size >= FLAG_BYTES) {
        probe_dtype<<<1, 256, 0, stream>>>((const unsigned short*)h, flag);
        edge_fused<<<E, 256, 0, stream>>>(h, src, dst, W1, b1, W2, b2, d_out, E, flag);
    } else {
        edge_fused<<<E, 256, 0, stream>>>(h, src, dst, W1, b1, W2, b2, d_out, E, nullptr);
    }
}

// Round 13
// 234.238 us; speedup vs baseline: 1.3465x; 1.3465x over previous
//
#include <hip/hip_runtime.h>
#include <math.h>

// N=100000, E=500000, D=256.
// Factored: concat(h[s],h[d])@W1 == h[s]@W1[0:256] + h[d]@W1[256:512]
//
// R21: REVERT to the R19 3-dispatch source (best measured: 233.7us).
// R20's cooperative fusion regressed (315us): (1) edge phase inside the
// fused kernel ran at 1 block/CU / 8 waves/CU (gemm's 160KB LDS footprint)
// vs ~20 waves/CU standalone -> edge is TLP-bound, +~35us; (2) the
// cooperative launch fell off the graph-capture fast path -> opaque
// launch overhead grew ~50us. Branch closed.
//
// Final structure (all phases proven by counters):
//   build_wt (512x256): self-probes dtype, publishes flag, transposes W1
//     into Wt[512][256] bf16.
//   gemm_pq (256x512, 160KB LDS, 1/CU): PQ8[N][512] fp8 = h @ W'.
//     Hybrid B residency: Bs rows 0-255 in 128KB LDS (staged once,
//     XOR-swizzled); rows 256-511 in regs (n32/wave). As[64][256] A-tile
//     streamed with reg prefetch; fp8 epilogue transposed through
//     As-scratch -> coalesced dwordx4 stores. 78us, FETCH 51MB, WRITE
//     50MB. Six restructures (all-reg-B, in-loop-B, 2-block, dbuf,
//     load-reorder) all failed to beat it — frozen.
//   edge_score (256 thr): 16 edges/wave dual-load: lane L loads 8B of
//     P[src] at byte (L&31)*8 and 8B of Q[dst] at 256+(L&31)*8;
//     select-merge xor1/2/4 + butterfly xor8/16. ~60us, latency-bound at
//     ~20 waves/CU (R12 measured the TLP sensitivity).
// fp8 error budget: absmax 0.0078125 << 0.0156 threshold.

typedef __attribute__((ext_vector_type(8))) short short8;
typedef __attribute__((ext_vector_type(2))) float floatx2;
typedef __attribute__((ext_vector_type(4))) float floatx4;
typedef __attribute__((ext_vector_type(16))) float floatx16;

#define D_FEAT 256
#define EPW 16

__device__ __forceinline__ float bf2f(unsigned short u) {
    union { unsigned u32; float f; } v; v.u32 = ((unsigned)u) << 16; return v.f;
}
__device__ __forceinline__ float lo16(unsigned u) {
    union { unsigned u32; float f; } v; v.u32 = u << 16; return v.f;
}
__device__ __forceinline__ float hi16(unsigned u) {
    union { unsigned u32; float f; } v; v.u32 = u & 0xffff0000u; return v.f;
}
__device__ __forceinline__ unsigned short f2bf(float f) {
    union { float f; unsigned u32; } v; v.f = f;
    unsigned x = v.u32;
    return (unsigned short)((x + 0x7fffu + ((x >> 16) & 1u)) >> 16);
}
__device__ __forceinline__ float sigmoid_safe(float r) {
    r = fminf(fmaxf(r, -30.f), 30.f);
    return 1.f / (1.f + expf(-r));
}
// 4 floats -> 4 fp8 e4m3 bytes (HW cvt, RNE)
__device__ __forceinline__ unsigned pack4_fp8(float a, float b, float c, float d) {
    int w = __builtin_amdgcn_cvt_pk_fp8_f32(a, b, 0, false);
    w = __builtin_amdgcn_cvt_pk_fp8_f32(c, d, w, true);
    return (unsigned)w;
}

// ---- dtype probe core: bf16 N(0,1) shorts have exp field in [100,140]
// ~100% of the time; fp32 reinterpreted as shorts only ~58%. Threshold 90%
// (1843/2048). Block-wide: 256 threads x 8 shorts, shfl+LDS reduce.
__device__ __forceinline__ int probe_block(const unsigned short* __restrict__ h,
                                           int tid) {
    __shared__ int cnt_s[4];
    int c = 0;
    #pragma unroll
    for (int i = 0; i < 8; ++i) {
        unsigned e = (h[tid * 8 + i] >> 7) & 0xFF;
        c += (e >= 100 && e <= 140) ? 1 : 0;
    }
    #pragma unroll
    for (int off = 32; off > 0; off >>= 1)
        c += __shfl_xor(c, off);
    if ((tid & 63) == 0) cnt_s[tid >> 6] = c;
    __syncthreads();
    int s = cnt_s[0] + cnt_s[1] + cnt_s[2] + cnt_s[3];
    return (s >= 1843) ? 1 : 0;
}

// Standalone probe (fallback path only).
__global__ __launch_bounds__(256) void probe_dtype(const unsigned short* __restrict__ h,
                                                   int* __restrict__ flag) {
    int isbf16 = probe_block(h, threadIdx.x);
    if (threadIdx.x == 0) flag[0] = isbf16;
}

// Wt[j][k] bf16 [512,256]: j<256 -> W1[k][j]; j>=256 -> W1[256+k][j-256]
// Each block self-probes h (deterministic); block 0 publishes flag.
__global__ __launch_bounds__(256) void build_wt(const unsigned short* __restrict__ h,
                                                const void* __restrict__ W1v,
                                                unsigned short* __restrict__ Wt,
                                                int* __restrict__ flag) {
    const int isbf16 = probe_block(h, threadIdx.x);
    if (blockIdx.x == 0 && threadIdx.x == 0) flag[0] = isbf16;
    int j = blockIdx.x, k = threadIdx.x;
    size_t idx = (j < 256) ? ((size_t)k * 256 + j) : ((size_t)(k + 256) * 256 + (j - 256));
    unsigned short v;
    if (isbf16) v = ((const unsigned short*)W1v)[idx];
    else        v = f2bf(((const float*)W1v)[idx]);
    Wt[(size_t)j * 256 + k] = v;
}

// PQ8[N][512] (fp8 e4m3) = h[N,256] @ W'[256,512] (Wt = W'^T, bf16 MFMA).
// R3 proven body: Bs = Wt rows 0..255 (LDS, staged once, swizzled);
// breg = Wt rows 256..511 (regs, n32/wave); A streamed, prefetch issued
// at K-loop start; fp8 epilogue via LDS transpose for coalesced stores.
__global__ __launch_bounds__(512, 2) void gemm_pq(const void* __restrict__ hv,
                                                  const unsigned short* __restrict__ Wt,
                                                  unsigned char* __restrict__ PQ8,
                                                  int N, const int* __restrict__ flag) {
    const int isbf16 = flag[0];
    __shared__ unsigned short Bs[256][256];   // 128 KB, resident, swizzled rows
    __shared__ unsigned short As[64][256];    // 32 KB: A tile / fp8 scratch
    // total 163840 B = full 160 KiB

    const int tid  = threadIdx.x;
    const int lane = tid & 63;
    const int wid  = tid >> 6;       // 0..7
    const int l32  = lane & 31;
    const int q2   = lane >> 5;

    // ---- Stage Bs once (Wt rows 0..255), swizzled write: conflict-free.
    {
        const int r = tid >> 1;                 // 0..255
        const unsigned cbase = (tid & 1) * 256; // byte half of 512 B row
        const char* srcp = (const char*)Wt + (size_t)r * 512 + cbase;
        char* dstb = (char*)&Bs[0][0] + (unsigned)r * 512;
        const unsigned sw = ((unsigned)r & 31) << 4;
        #pragma unroll
        for (int i = 0; i < 16; ++i) {
            short8 v = *(const short8*)(srcp + i * 16);
            *(short8*)(dstb + ((cbase + i * 16) ^ sw)) = v;
        }
    }

    // ---- Reg-B: Wt row (256 + wid*32 + l32), k-slot = ks*32 + q2*16 bytes.
    short8 breg[16];
    {
        const char* bp = (const char*)Wt + (size_t)(256 + wid * 32 + l32) * 512 + q2 * 16;
        #pragma unroll
        for (int ks = 0; ks < 16; ++ks)
            breg[ks] = *(const short8*)(bp + ks * 32);
    }

    // ---- A staging map: thread t -> row ar (0..63), 4 x 16 B at col ac.
    const int ar = tid >> 3;                 // 0..63
    const unsigned ac = (unsigned)(tid & 7) * 64;
    const unsigned aswz = ((unsigned)ar & 31) << 4;

    short8 pref[4];
    auto load_a = [&](int ms) {
        const int gm = ms * 64 + ar;
        if (isbf16) {
            #pragma unroll
            for (int j = 0; j < 4; ++j) {
                short8 v = {};
                if (gm < N)
                    v = *(const short8*)((const char*)hv + (size_t)gm * 512 + ac + j * 16);
                pref[j] = v;
            }
        } else {
            // fp32 correctness path: convert in place (not perf-critical).
            #pragma unroll
            for (int j = 0; j < 4; ++j) {
                short8 v = {};
                if (gm < N) {
                    const float* p = (const float*)hv + (size_t)gm * 256 + (ac + j * 16) / 2;
                    floatx4 f0 = *(const floatx4*)p;
                    floatx4 f1 = *(const floatx4*)(p + 4);
                    v[0] = (short)f2bf(f0.x); v[1] = (short)f2bf(f0.y);
                    v[2] = (short)f2bf(f0.z); v[3] = (short)f2bf(f0.w);
                    v[4] = (short)f2bf(f1.x); v[5] = (short)f2bf(f1.y);
                    v[6] = (short)f2bf(f1.z); v[7] = (short)f2bf(f1.w);
                }
                pref[j] = v;
            }
        }
    };

    const int NT = (N + 63) >> 6;
    const int GM = gridDim.x;
    if ((int)blockIdx.x < NT) load_a(blockIdx.x);

    for (int ms = blockIdx.x; ms < NT; ms += GM) {
        __syncthreads();   // bar1: prev iter's scratch readout done -> As writable
        {
            char* adst = (char*)&As[0][0] + (unsigned)ar * 512;
            #pragma unroll
            for (int j = 0; j < 4; ++j)
                *(short8*)(adst + ((ac + j * 16) ^ aswz)) = pref[j];
        }
        __syncthreads();   // bar2: As visible

        // Issue next tile's load here — covered by the K-loop below.
        const int msn = ms + GM;
        if (msn < NT) load_a(msn);

        floatx16 acc[2][2] = {};     // [m-half][0=LDS-n | 1=reg-n]
        #pragma unroll
        for (int ks = 0; ks < 16; ++ks) {
            const unsigned cb = ((unsigned)(ks * 32 + q2 * 16)) ^ ((unsigned)l32 << 4);
            short8 a0 = *(const short8*)((const char*)&As[0][0] + (unsigned)l32 * 512 + cb);
            short8 a1 = *(const short8*)((const char*)&As[0][0] + (unsigned)(32 + l32) * 512 + cb);
            short8 bl = *(const short8*)((const char*)&Bs[0][0] + (unsigned)(wid * 32 + l32) * 512 + cb);
            acc[0][0] = __builtin_amdgcn_mfma_f32_32x32x16_bf16(bl,       a0, acc[0][0], 0, 0, 0);
            acc[1][0] = __builtin_amdgcn_mfma_f32_32x32x16_bf16(bl,       a1, acc[1][0], 0, 0, 0);
            acc[0][1] = __builtin_amdgcn_mfma_f32_32x32x16_bf16(breg[ks], a0, acc[0][1], 0, 0, 0);
            acc[1][1] = __builtin_amdgcn_mfma_f32_32x32x16_bf16(breg[ks], a1, acc[1][1], 0, 0, 0);
        }

        __syncthreads();   // bar3: all As reads done -> reuse as fp8 scratch
        {
            unsigned char* scr = (unsigned char*)&As[0][0];
            #pragma unroll
            for (int mi = 0; mi < 2; ++mi) {
                const unsigned row = (unsigned)(mi * 32 + l32);
                const unsigned rs = (row & 31) << 4;
                #pragma unroll
                for (int nb = 0; nb < 2; ++nb) {
                    const unsigned nbase = (unsigned)(nb * 256 + wid * 32 + 4 * q2);
                    #pragma unroll
                    for (int g = 0; g < 4; ++g) {
                        unsigned w = pack4_fp8(acc[mi][nb][4 * g + 0], acc[mi][nb][4 * g + 1],
                                               acc[mi][nb][4 * g + 2], acc[mi][nb][4 * g + 3]);
                        const unsigned col = nbase + 8 * g;
                        *(unsigned*)(scr + ((row * 512 + col) ^ rs)) = w;
                    }
                }
            }
        }
        __syncthreads();   // bar4: scratch complete -> coalesced readout
        {
            const unsigned char* scr = (const unsigned char*)&As[0][0];
            const int gm = ms * 64 + ar;
            if (gm < N) {
                #pragma unroll
                for (int j = 0; j < 4; ++j) {
                    const unsigned col = ac + j * 16;
                    uint4 v = *(const uint4*)(scr + (((unsigned)ar * 512 + col) ^ aswz));
                    *(uint4*)(PQ8 + (size_t)gm * 512 + col) = v;
                }
            }
        }
    }
}

// R15 edge kernel (runtime-branch): 16 edges per wave, dual-load layout.
// Lane L (half h=L>>5) owns edges e0+2p+h (p=0..7): loads 8B of P from
// PQ8[src[e]] byte (L&31)*8 and 8B of Q from PQ8[dst[e]] byte 256+(L&31)*8.
// Each 32-lane half reduces its own edges: select-merge xor1/2/4 + butterfly
// xor8/16 (9 DS ops total). Lane (L&31)<8 stores edge e0+2*(L&7)+h.
__global__ __launch_bounds__(256) void edge_score(const unsigned char* __restrict__ PQ8,
                                                  const int* __restrict__ src,
                                                  const int* __restrict__ dst,
                                                  const void* __restrict__ b1v,
                                                  const void* __restrict__ W2v,
                                                  const void* __restrict__ b2v,
                                                  void* __restrict__ outv,
                                                  int E, const int* __restrict__ flag) {
    const int isbf16 = flag[0];
    const int wave = threadIdx.x >> 6;
    const int lane = threadIdx.x & 63;
    const int e0 = (blockIdx.x * 4 + wave) * EPW;
    if (e0 >= E) return;
    const int l32 = lane & 31;
    const int par = lane >> 5;           // 0: even edges, 1: odd edges

    // per-lane feature slice: features l32*8 .. +7
    float bf[8], wf[8];
    if (isbf16) {
        const uint4 bvr = *(const uint4*)((const unsigned short*)b1v + l32 * 8);
        const uint4 wvr = *(const uint4*)((const unsigned short*)W2v + l32 * 8);
        bf[0] = lo16(bvr.x); bf[1] = hi16(bvr.x); bf[2] = lo16(bvr.y); bf[3] = hi16(bvr.y);
        bf[4] = lo16(bvr.z); bf[5] = hi16(bvr.z); bf[6] = lo16(bvr.w); bf[7] = hi16(bvr.w);
        wf[0] = lo16(wvr.x); wf[1] = hi16(wvr.x); wf[2] = lo16(wvr.y); wf[3] = hi16(wvr.y);
        wf[4] = lo16(wvr.z); wf[5] = hi16(wvr.z); wf[6] = lo16(wvr.w); wf[7] = hi16(wvr.w);
    } else {
        const float* bp = (const float*)b1v + l32 * 8;
        const float* wp = (const float*)W2v + l32 * 8;
        #pragma unroll
        for (int t = 0; t < 8; ++t) { bf[t] = bp[t]; wf[t] = wp[t]; }
    }
    float bias2;
    if (isbf16) bias2 = bf2f(((const unsigned short*)b2v)[0]);
    else        bias2 = ((const float*)b2v)[0];

    int nsrc[8], ndst[8];
    #pragma unroll
    for (int p = 0; p < 8; ++p) {
        int e = e0 + 2 * p + par; if (e >= E) e = E - 1;
        nsrc[p] = src[e];
        ndst[p] = dst[e];
    }
    uint2 rp[8], rq[8];   // 16 x 8 B gathers in flight per lane
    #pragma unroll
    for (int p = 0; p < 8; ++p) {
        rp[p] = *(const uint2*)(PQ8 + (size_t)nsrc[p] * 512 + l32 * 8);
        rq[p] = *(const uint2*)(PQ8 + (size_t)ndst[p] * 512 + 256 + l32 * 8);
    }

    float res[8];
    #pragma unroll
    for (int p = 0; p < 8; ++p) {
        floatx2 p01 = __builtin_amdgcn_cvt_pk_f32_fp8((int)rp[p].x, false);
        floatx2 p23 = __builtin_amdgcn_cvt_pk_f32_fp8((int)rp[p].x, true);
        floatx2 p45 = __builtin_amdgcn_cvt_pk_f32_fp8((int)rp[p].y, false);
        floatx2 p67 = __builtin_amdgcn_cvt_pk_f32_fp8((int)rp[p].y, true);
        floatx2 q01 = __builtin_amdgcn_cvt_pk_f32_fp8((int)rq[p].x, false);
        floatx2 q23 = __builtin_amdgcn_cvt_pk_f32_fp8((int)rq[p].x, true);
        floatx2 q45 = __builtin_amdgcn_cvt_pk_f32_fp8((int)rq[p].y, false);
        floatx2 q67 = __builtin_amdgcn_cvt_pk_f32_fp8((int)rq[p].y, true);
        float v0 = fmaxf(p01.x + q01.x + bf[0], 0.f);
        float v1 = fmaxf(p01.y + q01.y + bf[1], 0.f);
        float v2 = fmaxf(p23.x + q23.x + bf[2], 0.f);
        float v3 = fmaxf(p23.y + q23.y + bf[3], 0.f);
        float v4 = fmaxf(p45.x + q45.x + bf[4], 0.f);
        float v5 = fmaxf(p45.y + q45.y + bf[5], 0.f);
        float v6 = fmaxf(p67.x + q67.x + bf[6], 0.f);
        float v7 = fmaxf(p67.y + q67.y + bf[7], 0.f);
        res[p] = v0 * wf[0] + v1 * wf[1] + v2 * wf[2] + v3 * wf[3]
               + v4 * wf[4] + v5 * wf[5] + v6 * wf[6] + v7 * wf[7];
    }

    // select-merge: fold 8 per-lane values over xor 1/2/4.
    float t4[4];
    #pragma unroll
    for (int k = 0; k < 4; ++k) {
        float a = res[2 * k], b = res[2 * k + 1];
        float own  = (lane & 1) ? b : a;
        float send = (lane & 1) ? a : b;
        t4[k] = own + __shfl_xor(send, 1);
    }
    float t2[2];
    #pragma unroll
    for (int k = 0; k < 2; ++k) {
        float a = t4[2 * k], b = t4[2 * k + 1];
        float own  = (lane & 2) ? b : a;
        float send = (lane & 2) ? a : b;
        t2[k] = own + __shfl_xor(send, 2);
    }
    float t1;
    {
        float a = t2[0], b = t2[1];
        float own  = (lane & 4) ? b : a;
        float send = (lane & 4) ? a : b;
        t1 = own + __shfl_xor(send, 4);
    }
    // butterfly completes the 32-chunk feature sum within each half
    t1 += __shfl_xor(t1, 8);
    t1 += __shfl_xor(t1, 16);
    // lane L holds the full dot for edge e0 + 2*(L&7) + (L>>5).

    if (l32 < 8) {
        const int e = e0 + 2 * (lane & 7) + par;
        if (e < E) {
            float r = sigmoid_safe(t1 + bias2);
            if (isbf16) ((unsigned short*)outv)[e] = f2bf(r);
            else        ((float*)outv)[e] = r;
        }
    }
}

// Zero-workspace fallback: one block per edge (full precision, no PQ).
__global__ __launch_bounds__(256) void edge_fused(const void* __restrict__ hv,
                                                  const int* __restrict__ src,
                                                  const int* __restrict__ dst,
                                                  const void* __restrict__ W1v,
                                                  const void* __restrict__ b1v,
                                                  const void* __restrict__ W2v,
                                                  const void* __restrict__ b2v,
                                                  void* __restrict__ outv,
                                                  int E, const int* __restrict__ flag) {
    const int isbf16 = flag ? flag[0] : 1;
    __shared__ float he[512];
    __shared__ float wsum[4];
    const int e = blockIdx.x;
    if (e >= E) return;
    const int t = threadIdx.x;
    const int s = src[e];
    const int d = dst[e];

    if (isbf16) {
        he[t]       = bf2f(((const unsigned short*)hv)[(size_t)s * 256 + t]);
        he[256 + t] = bf2f(((const unsigned short*)hv)[(size_t)d * 256 + t]);
    } else {
        he[t]       = ((const float*)hv)[(size_t)s * 256 + t];
        he[256 + t] = ((const float*)hv)[(size_t)d * 256 + t];
    }
    __syncthreads();

    float acc;
    if (isbf16) acc = bf2f(((const unsigned short*)b1v)[t]);
    else        acc = ((const float*)b1v)[t];

    #pragma unroll 8
    for (int k = 0; k < 512; ++k) {
        float w;
        if (isbf16) w = bf2f(((const unsigned short*)W1v)[(size_t)k * 256 + t]);
        else        w = ((const float*)W1v)[(size_t)k * 256 + t];
        acc += he[k] * w;
    }

    float w2;
    if (isbf16) w2 = bf2f(((const unsigned short*)W2v)[t]);
    else        w2 = ((const float*)W2v)[t];
    acc = fmaxf(acc, 0.f) * w2;

    #pragma unroll
    for (int off = 32; off > 0; off >>= 1)
        acc += __shfl_xor(acc, off);
    if ((t & 63) == 0) wsum[t >> 6] = acc;
    __syncthreads();

    if (t == 0) {
        float bias2;
        if (isbf16) bias2 = bf2f(((const unsigned short*)b2v)[0]);
        else        bias2 = ((const float*)b2v)[0];
        float r = sigmoid_safe(wsum[0] + wsum[1] + wsum[2] + wsum[3] + bias2);
        if (isbf16) ((unsigned short*)outv)[e] = f2bf(r);
        else        ((float*)outv)[e] = r;
    }
}

extern "C" void kernel_launch(void* const* d_in, const int* in_sizes, int n_in,
                              void* d_out, int out_size, void* d_ws, size_t ws_size,
                              hipStream_t stream) {
    const void* h  = d_in[0];
    const int* src = (const int*)d_in[1];
    const int* dst = (const int*)d_in[2];
    const void* W1 = d_in[3];
    const void* b1 = d_in[4];
    const void* W2 = d_in[5];
    const void* b2 = d_in[6];

    const int N = in_sizes[0] / D_FEAT;   // 100000
    const int E = in_sizes[1];            // 500000

    const size_t FLAG_BYTES = 256;
    const size_t wt_bytes  = (size_t)512 * D_FEAT * sizeof(unsigned short);
    const size_t pq_bytes  = (size_t)N * 512;   // fp8: 1 B/elem
    const size_t need = FLAG_BYTES + wt_bytes + pq_bytes;

    int* flag = (int*)d_ws;
    unsigned short* Wt = (unsigned short*)((char*)d_ws + FLAG_BYTES);
    unsigned char*  PQ8 = (unsigned char*)((char*)d_ws + FLAG_BYTES + wt_bytes);

    if (ws_size >= need) {
        // 3 dispatches: build_wt self-probes + publishes flag.
        build_wt<<<512, 256, 0, stream>>>((const unsigned short*)h, W1, Wt, flag);

        // 256 blocks (1/CU), 512 thr; each grid-strides ~6 m-subtiles of 64
        // rows, computing the full 512 N-cols (R3 proven config).
        gemm_pq<<<256, 512, 0, stream>>>(h, Wt, PQ8, N, flag);

        int egrid = (E + 4 * EPW - 1) / (4 * EPW);
        edge_score<<<egrid, 256, 0, stream>>>(PQ8, src, dst, b1, W2, b2, d_out, E, flag);
    } else if (ws_size >= FLAG_BYTES) {
        probe_dtype<<<1, 256, 0, stream>>>((const unsigned short*)h, flag);
        edge_fused<<<E, 256, 0, stream>>>(h, src, dst, W1, b1, W2, b2, d_out, E, flag);
    } else {
        edge_fused<<<E, 256, 0, stream>>>(h, src, dst, W1, b1, W2, b2, d_out, E, nullptr);
    }
}